// Round 2
// baseline (642.429 us; speedup 1.0000x reference)
//
#include <hip/hip_runtime.h>
#include <hip/hip_bf16.h>
#include <stdint.h>

// Problem constants
#define NTOK   64      // tokens per window
#define CDIM   256     // embed dim
#define NHEAD  8
#define DHEAD  32
#define NWIN   256     // windows per image (mask count)
#define BWIN   2048    // total windows
#define MROWS  131072  // BWIN*NTOK

typedef __attribute__((ext_vector_type(8))) short short8;
typedef __attribute__((ext_vector_type(4))) float f32x4;

__device__ __forceinline__ ushort f2bf(float f) {
  uint32_t u = __float_as_uint(f);
  u += 0x7fffu + ((u >> 16) & 1u);   // RNE
  return (ushort)(u >> 16);
}
__device__ __forceinline__ void unpack8(uint4 u, float* f) {
  f[0] = __uint_as_float(u.x << 16);
  f[1] = __uint_as_float(u.x & 0xffff0000u);
  f[2] = __uint_as_float(u.y << 16);
  f[3] = __uint_as_float(u.y & 0xffff0000u);
  f[4] = __uint_as_float(u.z << 16);
  f[5] = __uint_as_float(u.z & 0xffff0000u);
  f[6] = __uint_as_float(u.w << 16);
  f[7] = __uint_as_float(u.w & 0xffff0000u);
}

// async global->LDS, 16B per lane; LDS dest must be wave-uniform base (+lane*16 by HW)
__device__ __forceinline__ void gload_lds16(const ushort* g, ushort* l) {
  __builtin_amdgcn_global_load_lds(
      (const __attribute__((address_space(1))) void*)g,
      (__attribute__((address_space(3))) void*)l, 16, 0, 0);
}

// ---------------- tiny prep kernels ----------------

__global__ void k_cast_bf16(const float* __restrict__ src, ushort* __restrict__ dst, int n4) {
  int i = blockIdx.x * blockDim.x + threadIdx.x;
  int stride = gridDim.x * blockDim.x;
  for (; i < n4; i += stride) {
    float4 v = ((const float4*)src)[i];
    ushort4 o;
    o.x = f2bf(v.x); o.y = f2bf(v.y); o.z = f2bf(v.z); o.w = f2bf(v.w);
    ((ushort4*)dst)[i] = o;
  }
}

// src[K][N] fp32 -> dst[N][K] bf16
__global__ void k_transpose_bf16(const float* __restrict__ src, ushort* __restrict__ dst, int K, int N) {
  int idx = blockIdx.x * 256 + threadIdx.x;
  if (idx < N * K) {
    int n = idx / K, k = idx - n * K;
    dst[idx] = f2bf(src[(size_t)k * N + n]);
  }
}

// CPB MLP: bias_table[225][8]
__global__ void k_cpb(const float* __restrict__ ct, const float* __restrict__ w1,
                      const float* __restrict__ b1, const float* __restrict__ w2,
                      float* __restrict__ out) {
  int p = blockIdx.x, t = threadIdx.x;
  float c0 = ct[p * 2], c1 = ct[p * 2 + 1];
  float acc[8];
#pragma unroll
  for (int h = 0; h < 8; ++h) acc[h] = 0.f;
  for (int j = t; j < 512; j += 256) {
    float hj = fmaxf(0.f, fmaf(c0, w1[j], fmaf(c1, w1[512 + j], b1[j])));
#pragma unroll
    for (int h = 0; h < 8; ++h) acc[h] = fmaf(hj, w2[j * 8 + h], acc[h]);
  }
#pragma unroll
  for (int off = 1; off < 64; off <<= 1)
#pragma unroll
    for (int h = 0; h < 8; ++h) acc[h] += __shfl_xor(acc[h], off, 64);
  __shared__ float red[4][8];
  if ((t & 63) == 0)
#pragma unroll
    for (int h = 0; h < 8; ++h) red[t >> 6][h] = acc[h];
  __syncthreads();
  if (t < 8) out[p * 8 + t] = red[0][t] + red[1][t] + red[2][t] + red[3][t];
}

// relbC in MFMA C-fragment order: idx = ((((h*4+mt)*4+nt)*4+g)*16+l16)*4+reg
// value = 16*sigmoid(bias_table[rpi[r*64+c]][h]), r = mt*16+g*4+reg, c = nt*16+l16
__global__ void k_relbC(const float* __restrict__ bt, const int* __restrict__ rpi,
                        float* __restrict__ out) {
  int idx = blockIdx.x * 256 + threadIdx.x;  // 32768 total
  int reg = idx & 3, l16 = (idx >> 2) & 15, g = (idx >> 6) & 3;
  int nt = (idx >> 8) & 3, mt = (idx >> 10) & 3, h = idx >> 12;
  int r = mt * 16 + g * 4 + reg, c = nt * 16 + l16;
  float v = bt[rpi[r * 64 + c] * 8 + h];
  out[idx] = 16.0f / (1.0f + __expf(-v));
}

// mask bits, packed for one-uint4-per-wave loads in attn:
// out[wi*1024 + (g*16+l16)*16 + (mt*4+nt)] : bit reg = (mask[wi][r][c] == 0)
// with r = mt*16+g*4+reg, c = nt*16+l16.  (mask values are exactly 0 or -100)
__global__ void k_maskBits(const float* __restrict__ mask, unsigned char* __restrict__ out) {
  int idx = blockIdx.x * 256 + threadIdx.x;  // 262144 total
  int b = idx & 15;            // mt*4+nt
  int q = (idx >> 4) & 63;     // g*16+l16
  int wi = idx >> 10;
  int mt = b >> 2, nt = b & 3, g = q >> 4, l16 = q & 15;
  unsigned char v = 0;
#pragma unroll
  for (int reg = 0; reg < 4; ++reg) {
    int r = mt * 16 + g * 4 + reg, c = nt * 16 + l16;
    if (mask[(size_t)wi * 4096 + r * 64 + c] == 0.0f) v |= (unsigned char)(1 << reg);
  }
  out[idx] = v;
}

// ---------------- MFMA GEMM: C[M][N] = A[M][K] * BT[N][K]^T ----------------
// Staging via global_load_lds (linear LDS dest, pre-swizzled global source col):
// LDS slot (m,c) holds global column c^(m&7)  -> identical content to the old
// reg-staged XOR-swizzled store, so the ds_read path is unchanged.
template <int MODE>
__global__ __launch_bounds__(256, 2) void gemm_bt(const ushort* __restrict__ A,
                                                  const ushort* __restrict__ BT,
                                                  void* __restrict__ Cout,
                                                  const float* __restrict__ bias0,
                                                  const float* __restrict__ bias1,
                                                  int K, int N) {
  __shared__ ushort As[128 * 64];
  __shared__ ushort Bs[128 * 64];
  const int t = threadIdx.x;

  // bijective XCD-aware swizzle (nwg % 8 == 0 in all our launches)
  const int gx = gridDim.x;
  int wg = blockIdx.y * gx + blockIdx.x;
  const int nwg = gx * gridDim.y;
  if ((nwg & 7) == 0) wg = (wg & 7) * (nwg >> 3) + (wg >> 3);
  const int bm = wg / gx, bn = wg - bm * gx;

  const int wv = t >> 6, lane = t & 63, quad = lane >> 4, l16 = lane & 15;
  const int mbase = (wv & 1) * 64, nbase = (wv >> 1) * 64;

  f32x4 acc[4][4] = {};

  const int nkt = K >> 6;
  for (int kt = 0; kt < nkt; ++kt) {
    __syncthreads();
#pragma unroll
    for (int i = 0; i < 4; ++i) {
      int idx = i * 256 + t;
      int m = idx >> 3, c = idx & 7;
      int cg = c ^ (m & 7);                       // pre-swizzled source column
      int ldsoff = (i * 256 + (t & ~63)) * 8;     // wave-uniform base (ushorts)
      gload_lds16(A + (size_t)(bm * 128 + m) * K + kt * 64 + cg * 8, As + ldsoff);
      gload_lds16(BT + (size_t)(bn * 128 + m) * K + kt * 64 + cg * 8, Bs + ldsoff);
    }
    __syncthreads();
#pragma unroll
    for (int k2 = 0; k2 < 2; ++k2) {
      const int cidx = (k2 * 4 + quad) ^ (l16 & 7);
      short8 a[4], b[4];
#pragma unroll
      for (int mt = 0; mt < 4; ++mt)
        a[mt] = *(const short8*)(As + ((mbase + mt * 16 + l16) * 8 + cidx) * 8);
#pragma unroll
      for (int nt = 0; nt < 4; ++nt)
        b[nt] = *(const short8*)(Bs + ((nbase + nt * 16 + l16) * 8 + cidx) * 8);
#pragma unroll
      for (int mt = 0; mt < 4; ++mt)
#pragma unroll
        for (int nt = 0; nt < 4; ++nt)
          acc[mt][nt] = __builtin_amdgcn_mfma_f32_16x16x32_bf16(a[mt], b[nt], acc[mt][nt], 0, 0, 0);
    }
  }

#pragma unroll
  for (int mt = 0; mt < 4; ++mt)
#pragma unroll
    for (int nt = 0; nt < 4; ++nt) {
      int j = bn * 128 + nbase + nt * 16 + l16;
      int gm = bm * 128 + mbase + mt * 16 + quad * 4;
      float bs;
      if (MODE == 0) bs = (j < 256) ? bias0[j] : ((j < 512) ? 0.0f : bias1[j - 512]);
      else bs = bias0[j];
#pragma unroll
      for (int i2 = 0; i2 < 4; ++i2) {
        float v = acc[mt][nt][i2] + bs;
        size_t off = (size_t)(gm + i2) * N + j;
        if (MODE == 0) ((ushort*)Cout)[off] = f2bf(v);
        else ((float*)Cout)[off] = v;
      }
    }
}

// ---------------- MFMA attention ----------------
// 1 block / window, 4 fully-independent waves (wave wv owns head pass*4+wv).
// NO __syncthreads: every LDS buffer is per-wave private; DS pipe is in-order
// within a wave, compiler inserts lgkmcnt waits.
// Q/K fragments loaded DIRECTLY from global (16B/lane); cosine L2-norm done
// in-register via shfl_xor(16)+shfl_xor(32) across the 4 g-lanes of one token.
// Mask applied from a packed bitmask (one uint4 per wave per pass).
// __launch_bounds__(256,3): VGPR cap ~170 -> no spill (round 1's (256,4)
// capped at 128 and spilled ~450MB of scratch traffic), 3 blocks/CU.
__global__ __launch_bounds__(256, 3) void k_attn_mfma(const ushort* __restrict__ qkv,
                                                      const unsigned char* __restrict__ maskN,
                                                      const float* __restrict__ ls,
                                                      const float* __restrict__ relbC,
                                                      ushort* __restrict__ aob) {
  __shared__ ushort Vt[4][32][72];
  __shared__ ushort Ps[4][64][40];
  const int b = blockIdx.x, t = threadIdx.x;
  const int wi = b & (NWIN - 1);
  const int wv = t >> 6, lane = t & 63;
  const int g = lane >> 4, l16 = lane & 15;
  const size_t rowb = (size_t)b * 64;

  for (int pass = 0; pass < 2; ++pass) {
    const int h = pass * 4 + wv;

    // ---- mask bits for this (window, lane): 16 nibbles, one per (mt,nt) ----
    const uint4 mbits = *(const uint4*)(maskN + (size_t)wi * 1024 + (g * 16 + l16) * 16);
    const unsigned char* mb = (const unsigned char*)&mbits;

    // ---- V -> Vt[wv] (transposed; per-wave private) ----
    {
      const int tok = lane;
      const size_t base = (rowb + tok) * 768 + 512 + h * 32;
      union { uint4 u[4]; ushort s[32]; } raw;
      raw.u[0] = *(const uint4*)(qkv + base);
      raw.u[1] = *(const uint4*)(qkv + base + 8);
      raw.u[2] = *(const uint4*)(qkv + base + 16);
      raw.u[3] = *(const uint4*)(qkv + base + 24);
#pragma unroll
      for (int d = 0; d < 32; ++d) Vt[wv][d][tok] = raw.s[d];
    }

    // ---- Q fragments: direct global load + in-register norm (+ logit scale) ----
    const float sc = __expf(fminf(ls[h], 4.6051701859880914f));
    short8 qfr[4], kfr[4];
#pragma unroll
    for (int mt = 0; mt < 4; ++mt) {
      uint4 r = *(const uint4*)(qkv + (rowb + mt * 16 + l16) * 768 + h * 32 + g * 8);
      float f[8];
      unpack8(r, f);
      float s = 0.f;
#pragma unroll
      for (int j = 0; j < 8; ++j) s = fmaf(f[j], f[j], s);
      s += __shfl_xor(s, 16, 64);
      s += __shfl_xor(s, 32, 64);
      const float fac = sc / fmaxf(sqrtf(s), 1e-12f);
      union { short8 v; ushort us[8]; } o;
#pragma unroll
      for (int j = 0; j < 8; ++j) o.us[j] = f2bf(f[j] * fac);
      qfr[mt] = o.v;
    }
    // ---- K fragments: same, without logit scale ----
#pragma unroll
    for (int nt = 0; nt < 4; ++nt) {
      uint4 r = *(const uint4*)(qkv + (rowb + nt * 16 + l16) * 768 + 256 + h * 32 + g * 8);
      float f[8];
      unpack8(r, f);
      float s = 0.f;
#pragma unroll
      for (int j = 0; j < 8; ++j) s = fmaf(f[j], f[j], s);
      s += __shfl_xor(s, 16, 64);
      s += __shfl_xor(s, 32, 64);
      const float fac = 1.0f / fmaxf(sqrtf(s), 1e-12f);
      union { short8 v; ushort us[8]; } o;
#pragma unroll
      for (int j = 0; j < 8; ++j) o.us[j] = f2bf(f[j] * fac);
      kfr[nt] = o.v;
    }

    // ---- S = Qn * Kn^T  (16 mfma, K=32 in one step) ----
    f32x4 sv[4][4];
    const f32x4 zero = {0.f, 0.f, 0.f, 0.f};
#pragma unroll
    for (int mt = 0; mt < 4; ++mt)
#pragma unroll
      for (int nt = 0; nt < 4; ++nt)
        sv[mt][nt] = __builtin_amdgcn_mfma_f32_16x16x32_bf16(qfr[mt], kfr[nt], zero, 0, 0, 0);

    // ---- + relb (C-frag float4) + mask (bit -> 0 / -100) ----
#pragma unroll
    for (int mt = 0; mt < 4; ++mt)
#pragma unroll
      for (int nt = 0; nt < 4; ++nt) {
        float4 rb = *(const float4*)(relbC + (size_t)(((h * 4 + mt) * 4 + nt) * 4 + g) * 64 + l16 * 4);
        const unsigned char nb = mb[mt * 4 + nt];
        sv[mt][nt][0] += rb.x + ((nb & 1) ? 0.f : -100.f);
        sv[mt][nt][1] += rb.y + ((nb & 2) ? 0.f : -100.f);
        sv[mt][nt][2] += rb.z + ((nb & 4) ? 0.f : -100.f);
        sv[mt][nt][3] += rb.w + ((nb & 8) ? 0.f : -100.f);
      }

    // ---- softmax over rows (row r = mt*16 + g*4 + reg; 64 cols over nt,l16) ----
    float mx[4][4], inv[4][4];
#pragma unroll
    for (int mt = 0; mt < 4; ++mt)
#pragma unroll
      for (int reg = 0; reg < 4; ++reg) {
        float m = fmaxf(fmaxf(sv[mt][0][reg], sv[mt][1][reg]),
                        fmaxf(sv[mt][2][reg], sv[mt][3][reg]));
#pragma unroll
        for (int st = 1; st < 16; st <<= 1) m = fmaxf(m, __shfl_xor(m, st, 64));
        mx[mt][reg] = m;
      }
#pragma unroll
    for (int mt = 0; mt < 4; ++mt)
#pragma unroll
      for (int nt = 0; nt < 4; ++nt)
#pragma unroll
        for (int reg = 0; reg < 4; ++reg)
          sv[mt][nt][reg] = __expf(sv[mt][nt][reg] - mx[mt][reg]);
#pragma unroll
    for (int mt = 0; mt < 4; ++mt)
#pragma unroll
      for (int reg = 0; reg < 4; ++reg) {
        float s = sv[mt][0][reg] + sv[mt][1][reg] + sv[mt][2][reg] + sv[mt][3][reg];
#pragma unroll
        for (int st = 1; st < 16; st <<= 1) s += __shfl_xor(s, st, 64);
        inv[mt][reg] = 1.0f / s;
      }

    // ---- PV: P (C-layout) -> per-wave LDS -> A-frags; O += P * V ----
    f32x4 ov[4][2] = {};
#pragma unroll
    for (int kt = 0; kt < 2; ++kt) {
#pragma unroll
      for (int mt = 0; mt < 4; ++mt)
#pragma unroll
        for (int reg = 0; reg < 4; ++reg)
#pragma unroll
          for (int tjh = 0; tjh < 2; ++tjh)
            Ps[wv][mt * 16 + g * 4 + reg][tjh * 16 + l16] = f2bf(sv[mt][kt * 2 + tjh][reg]);
      short8 pf[4], vf[2];
#pragma unroll
      for (int mt = 0; mt < 4; ++mt) pf[mt] = *(const short8*)&Ps[wv][mt * 16 + l16][g * 8];
#pragma unroll
      for (int n2 = 0; n2 < 2; ++n2) vf[n2] = *(const short8*)&Vt[wv][n2 * 16 + l16][kt * 32 + g * 8];
#pragma unroll
      for (int mt = 0; mt < 4; ++mt)
#pragma unroll
        for (int n2 = 0; n2 < 2; ++n2)
          ov[mt][n2] = __builtin_amdgcn_mfma_f32_16x16x32_bf16(pf[mt], vf[n2], ov[mt][n2], 0, 0, 0);
    }

    // ---- epilogue: normalize rows, store bf16 ----
#pragma unroll
    for (int mt = 0; mt < 4; ++mt)
#pragma unroll
      for (int n2 = 0; n2 < 2; ++n2)
#pragma unroll
        for (int reg = 0; reg < 4; ++reg) {
          int r = mt * 16 + g * 4 + reg;
          float o = ov[mt][n2][reg] * inv[mt][reg];
          aob[((size_t)b * 64 + r) * 256 + h * 32 + n2 * 16 + l16] = f2bf(o);
        }
  }
}

// ---------------- launch ----------------

extern "C" void kernel_launch(void* const* d_in, const int* in_sizes, int n_in,
                              void* d_out, int out_size, void* d_ws, size_t ws_size,
                              hipStream_t stream) {
  const float* x      = (const float*)d_in[0];
  const float* mask   = (const float*)d_in[1];
  const float* qkv_w  = (const float*)d_in[2];
  const float* q_bias = (const float*)d_in[3];
  const float* v_bias = (const float*)d_in[4];
  const float* lscale = (const float*)d_in[5];
  const float* ctbl   = (const float*)d_in[6];
  const float* m1w    = (const float*)d_in[7];
  const float* m1b    = (const float*)d_in[8];
  const float* m2w    = (const float*)d_in[9];
  const float* projw  = (const float*)d_in[10];
  const float* projb  = (const float*)d_in[11];
  const int*   rpi    = (const int*)d_in[12];

  char* w = (char*)d_ws;
  float*  bias_table = (float*)(w + 0);               //    7200 B
  float*  relbC      = (float*)(w + 8192);            //  131072 B
  unsigned char* maskN = (unsigned char*)(w + 139264); //  262144 B
  ushort* qkvWT      = (ushort*)(w + 4333568);        //  393216 B  [768][256] bf16
  ushort* projWT     = (ushort*)(w + 4726784);        //  131072 B  [256][256] bf16
  ushort* xb         = (ushort*)(w + 4857856);        // 67108864 B [131072][256] bf16
  ushort* qkvb       = (ushort*)(w + 71966720ull);    // 201326592 B [131072][768] bf16
  ushort* aob        = (ushort*)(w + 273293312ull);   // 67108864 B [131072][256] bf16
  (void)ws_size; (void)n_in; (void)in_sizes; (void)out_size;

  k_cast_bf16<<<4096, 256, 0, stream>>>(x, xb, MROWS * CDIM / 4);
  k_transpose_bf16<<<768, 256, 0, stream>>>(qkv_w, qkvWT, 256, 768);
  k_transpose_bf16<<<256, 256, 0, stream>>>(projw, projWT, 256, 256);
  k_cpb<<<225, 256, 0, stream>>>(ctbl, m1w, m1b, m2w, bias_table);
  k_relbC<<<128, 256, 0, stream>>>(bias_table, rpi, relbC);
  k_maskBits<<<1024, 256, 0, stream>>>(mask, maskN);

  gemm_bt<0><<<dim3(6, 1024), 256, 0, stream>>>(xb, qkvWT, qkvb, q_bias, v_bias, 256, 768);
  k_attn_mfma<<<BWIN, 256, 0, stream>>>(qkvb, maskN, lscale, relbC, aob);
  gemm_bt<1><<<dim3(2, 1024), 256, 0, stream>>>(aob, projWT, d_out, projb, nullptr, 256, 256);
}

// Round 3
// 529.713 us; speedup vs baseline: 1.2128x; 1.2128x over previous
//
#include <hip/hip_runtime.h>
#include <hip/hip_bf16.h>
#include <stdint.h>

// Problem constants
#define NTOK   64      // tokens per window
#define CDIM   256     // embed dim
#define NHEAD  8
#define DHEAD  32
#define NWIN   256     // windows per image (mask count)
#define BWIN   2048    // total windows
#define MROWS  131072  // BWIN*NTOK

typedef __attribute__((ext_vector_type(8))) short short8;
typedef __attribute__((ext_vector_type(4))) float f32x4;

__device__ __forceinline__ ushort f2bf(float f) {
  uint32_t u = __float_as_uint(f);
  u += 0x7fffu + ((u >> 16) & 1u);   // RNE
  return (ushort)(u >> 16);
}
__device__ __forceinline__ void unpack8(uint4 u, float* f) {
  f[0] = __uint_as_float(u.x << 16);
  f[1] = __uint_as_float(u.x & 0xffff0000u);
  f[2] = __uint_as_float(u.y << 16);
  f[3] = __uint_as_float(u.y & 0xffff0000u);
  f[4] = __uint_as_float(u.z << 16);
  f[5] = __uint_as_float(u.z & 0xffff0000u);
  f[6] = __uint_as_float(u.w << 16);
  f[7] = __uint_as_float(u.w & 0xffff0000u);
}

// async global->LDS, 16B per lane; LDS dest must be wave-uniform base (+lane*16 by HW)
__device__ __forceinline__ void gload_lds16(const ushort* g, ushort* l) {
  __builtin_amdgcn_global_load_lds(
      (const __attribute__((address_space(1))) void*)g,
      (__attribute__((address_space(3))) void*)l, 16, 0, 0);
}

// ---------------- tiny prep kernels ----------------

__global__ void k_cast_bf16(const float* __restrict__ src, ushort* __restrict__ dst, int n4) {
  int i = blockIdx.x * blockDim.x + threadIdx.x;
  int stride = gridDim.x * blockDim.x;
  for (; i < n4; i += stride) {
    float4 v = ((const float4*)src)[i];
    ushort4 o;
    o.x = f2bf(v.x); o.y = f2bf(v.y); o.z = f2bf(v.z); o.w = f2bf(v.w);
    ((ushort4*)dst)[i] = o;
  }
}

// src[K][N] fp32 -> dst[N][K] bf16
__global__ void k_transpose_bf16(const float* __restrict__ src, ushort* __restrict__ dst, int K, int N) {
  int idx = blockIdx.x * 256 + threadIdx.x;
  if (idx < N * K) {
    int n = idx / K, k = idx - n * K;
    dst[idx] = f2bf(src[(size_t)k * N + n]);
  }
}

// CPB MLP: bias_table[225][8]
__global__ void k_cpb(const float* __restrict__ ct, const float* __restrict__ w1,
                      const float* __restrict__ b1, const float* __restrict__ w2,
                      float* __restrict__ out) {
  int p = blockIdx.x, t = threadIdx.x;
  float c0 = ct[p * 2], c1 = ct[p * 2 + 1];
  float acc[8];
#pragma unroll
  for (int h = 0; h < 8; ++h) acc[h] = 0.f;
  for (int j = t; j < 512; j += 256) {
    float hj = fmaxf(0.f, fmaf(c0, w1[j], fmaf(c1, w1[512 + j], b1[j])));
#pragma unroll
    for (int h = 0; h < 8; ++h) acc[h] = fmaf(hj, w2[j * 8 + h], acc[h]);
  }
#pragma unroll
  for (int off = 1; off < 64; off <<= 1)
#pragma unroll
    for (int h = 0; h < 8; ++h) acc[h] += __shfl_xor(acc[h], off, 64);
  __shared__ float red[4][8];
  if ((t & 63) == 0)
#pragma unroll
    for (int h = 0; h < 8; ++h) red[t >> 6][h] = acc[h];
  __syncthreads();
  if (t < 8) out[p * 8 + t] = red[0][t] + red[1][t] + red[2][t] + red[3][t];
}

// relbC in MFMA C-fragment order: idx = ((((h*4+mt)*4+nt)*4+g)*16+l16)*4+reg
// value = 16*sigmoid(bias_table[rpi[r*64+c]][h]), r = mt*16+g*4+reg, c = nt*16+l16
__global__ void k_relbC(const float* __restrict__ bt, const int* __restrict__ rpi,
                        float* __restrict__ out) {
  int idx = blockIdx.x * 256 + threadIdx.x;  // 32768 total
  int reg = idx & 3, l16 = (idx >> 2) & 15, g = (idx >> 6) & 3;
  int nt = (idx >> 8) & 3, mt = (idx >> 10) & 3, h = idx >> 12;
  int r = mt * 16 + g * 4 + reg, c = nt * 16 + l16;
  float v = bt[rpi[r * 64 + c] * 8 + h];
  out[idx] = 16.0f / (1.0f + __expf(-v));
}

// mask bits, packed for one-uint4-per-wave loads in attn:
// out[wi*1024 + (g*16+l16)*16 + (mt*4+nt)] : bit reg = (mask[wi][r][c] == 0)
// with r = mt*16+g*4+reg, c = nt*16+l16.  (mask values are exactly 0 or -100)
__global__ void k_maskBits(const float* __restrict__ mask, unsigned char* __restrict__ out) {
  int idx = blockIdx.x * 256 + threadIdx.x;  // 262144 total
  int b = idx & 15;            // mt*4+nt
  int q = (idx >> 4) & 63;     // g*16+l16
  int wi = idx >> 10;
  int mt = b >> 2, nt = b & 3, g = q >> 4, l16 = q & 15;
  unsigned char v = 0;
#pragma unroll
  for (int reg = 0; reg < 4; ++reg) {
    int r = mt * 16 + g * 4 + reg, c = nt * 16 + l16;
    if (mask[(size_t)wi * 4096 + r * 64 + c] == 0.0f) v |= (unsigned char)(1 << reg);
  }
  out[idx] = v;
}

// ---------------- MFMA GEMM: C[M][N] = A[M][K] * BT[N][K]^T ----------------
// Staging via global_load_lds (linear LDS dest, pre-swizzled global source col):
// LDS slot (m,c) holds global column c^(m&7)  -> identical content to the old
// reg-staged XOR-swizzled store, so the ds_read path is unchanged.
template <int MODE>
__global__ __launch_bounds__(256, 2) void gemm_bt(const ushort* __restrict__ A,
                                                  const ushort* __restrict__ BT,
                                                  void* __restrict__ Cout,
                                                  const float* __restrict__ bias0,
                                                  const float* __restrict__ bias1,
                                                  int K, int N) {
  __shared__ ushort As[128 * 64];
  __shared__ ushort Bs[128 * 64];
  const int t = threadIdx.x;

  // bijective XCD-aware swizzle (nwg % 8 == 0 in all our launches)
  const int gx = gridDim.x;
  int wg = blockIdx.y * gx + blockIdx.x;
  const int nwg = gx * gridDim.y;
  if ((nwg & 7) == 0) wg = (wg & 7) * (nwg >> 3) + (wg >> 3);
  const int bm = wg / gx, bn = wg - bm * gx;

  const int wv = t >> 6, lane = t & 63, quad = lane >> 4, l16 = lane & 15;
  const int mbase = (wv & 1) * 64, nbase = (wv >> 1) * 64;

  f32x4 acc[4][4] = {};

  const int nkt = K >> 6;
  for (int kt = 0; kt < nkt; ++kt) {
    __syncthreads();
#pragma unroll
    for (int i = 0; i < 4; ++i) {
      int idx = i * 256 + t;
      int m = idx >> 3, c = idx & 7;
      int cg = c ^ (m & 7);                       // pre-swizzled source column
      int ldsoff = (i * 256 + (t & ~63)) * 8;     // wave-uniform base (ushorts)
      gload_lds16(A + (size_t)(bm * 128 + m) * K + kt * 64 + cg * 8, As + ldsoff);
      gload_lds16(BT + (size_t)(bn * 128 + m) * K + kt * 64 + cg * 8, Bs + ldsoff);
    }
    __syncthreads();
#pragma unroll
    for (int k2 = 0; k2 < 2; ++k2) {
      const int cidx = (k2 * 4 + quad) ^ (l16 & 7);
      short8 a[4], b[4];
#pragma unroll
      for (int mt = 0; mt < 4; ++mt)
        a[mt] = *(const short8*)(As + ((mbase + mt * 16 + l16) * 8 + cidx) * 8);
#pragma unroll
      for (int nt = 0; nt < 4; ++nt)
        b[nt] = *(const short8*)(Bs + ((nbase + nt * 16 + l16) * 8 + cidx) * 8);
#pragma unroll
      for (int mt = 0; mt < 4; ++mt)
#pragma unroll
        for (int nt = 0; nt < 4; ++nt)
          acc[mt][nt] = __builtin_amdgcn_mfma_f32_16x16x32_bf16(a[mt], b[nt], acc[mt][nt], 0, 0, 0);
    }
  }

#pragma unroll
  for (int mt = 0; mt < 4; ++mt)
#pragma unroll
    for (int nt = 0; nt < 4; ++nt) {
      int j = bn * 128 + nbase + nt * 16 + l16;
      int gm = bm * 128 + mbase + mt * 16 + quad * 4;
      float bs;
      if (MODE == 0) bs = (j < 256) ? bias0[j] : ((j < 512) ? 0.0f : bias1[j - 512]);
      else bs = bias0[j];
#pragma unroll
      for (int i2 = 0; i2 < 4; ++i2) {
        float v = acc[mt][nt][i2] + bs;
        size_t off = (size_t)(gm + i2) * N + j;
        if (MODE == 0) ((ushort*)Cout)[off] = f2bf(v);
        else ((float*)Cout)[off] = v;
      }
    }
}

// ---------------- MFMA attention ----------------
// 1 block / window, 4 fully-independent waves (wave wv owns head pass*4+wv).
// NO __syncthreads: every LDS buffer is per-wave private; DS pipe is in-order
// within a wave, compiler inserts lgkmcnt waits.
// Q/K fragments loaded DIRECTLY from global (16B/lane); cosine L2-norm done
// in-register via shfl_xor(16)+shfl_xor(32) across the 4 g-lanes of one token.
// Mask applied from a packed bitmask (one uint4 per wave, hoisted).
// Register budget: gfx950 unified VGPR/AGPR file -> __launch_bounds__ second
// arg w gives TOTAL cap 512/(2w) incl. accumulators. (256,3) capped at 170 and
// spilled ~150MB (round 2: WRITE_SIZE 215MB vs 66 legit). Use (256,2) -> cap
// 256; and shrink peak liveness: P is packed to bf16 (with 1/sum folded in)
// right after exp, freeing sv (64 AGPRs) + inv (16) before the PV loop.
__global__ __launch_bounds__(256, 2) void k_attn_mfma(const ushort* __restrict__ qkv,
                                                      const unsigned char* __restrict__ maskN,
                                                      const float* __restrict__ ls,
                                                      const float* __restrict__ relbC,
                                                      ushort* __restrict__ aob) {
  __shared__ ushort Vt[4][32][72];
  __shared__ ushort Ps[4][64][40];
  const int b = blockIdx.x, t = threadIdx.x;
  const int wi = b & (NWIN - 1);
  const int wv = t >> 6, lane = t & 63;
  const int g = lane >> 4, l16 = lane & 15;
  const size_t rowb = (size_t)b * 64;

  // ---- mask bits for this (window, lane): 16 nibbles, one per (mt,nt) ----
  const uint4 mbits = *(const uint4*)(maskN + (size_t)wi * 1024 + (g * 16 + l16) * 16);
  const unsigned char* mb = (const unsigned char*)&mbits;

  for (int pass = 0; pass < 2; ++pass) {
    const int h = pass * 4 + wv;

    // ---- V -> Vt[wv] (transposed; per-wave private) ----
    {
      const int tok = lane;
      const size_t base = (rowb + tok) * 768 + 512 + h * 32;
      union { uint4 u[4]; ushort s[32]; } raw;
      raw.u[0] = *(const uint4*)(qkv + base);
      raw.u[1] = *(const uint4*)(qkv + base + 8);
      raw.u[2] = *(const uint4*)(qkv + base + 16);
      raw.u[3] = *(const uint4*)(qkv + base + 24);
#pragma unroll
      for (int d = 0; d < 32; ++d) Vt[wv][d][tok] = raw.s[d];
    }

    // ---- Q fragments: direct global load + in-register norm (+ logit scale) ----
    const float sc = __expf(fminf(ls[h], 4.6051701859880914f));
    short8 qfr[4], kfr[4];
#pragma unroll
    for (int mt = 0; mt < 4; ++mt) {
      uint4 r = *(const uint4*)(qkv + (rowb + mt * 16 + l16) * 768 + h * 32 + g * 8);
      float f[8];
      unpack8(r, f);
      float s = 0.f;
#pragma unroll
      for (int j = 0; j < 8; ++j) s = fmaf(f[j], f[j], s);
      s += __shfl_xor(s, 16, 64);
      s += __shfl_xor(s, 32, 64);
      const float fac = sc / fmaxf(sqrtf(s), 1e-12f);
      union { short8 v; ushort us[8]; } o;
#pragma unroll
      for (int j = 0; j < 8; ++j) o.us[j] = f2bf(f[j] * fac);
      qfr[mt] = o.v;
    }
    // ---- K fragments: same, without logit scale ----
#pragma unroll
    for (int nt = 0; nt < 4; ++nt) {
      uint4 r = *(const uint4*)(qkv + (rowb + nt * 16 + l16) * 768 + 256 + h * 32 + g * 8);
      float f[8];
      unpack8(r, f);
      float s = 0.f;
#pragma unroll
      for (int j = 0; j < 8; ++j) s = fmaf(f[j], f[j], s);
      s += __shfl_xor(s, 16, 64);
      s += __shfl_xor(s, 32, 64);
      const float fac = 1.0f / fmaxf(sqrtf(s), 1e-12f);
      union { short8 v; ushort us[8]; } o;
#pragma unroll
      for (int j = 0; j < 8; ++j) o.us[j] = f2bf(f[j] * fac);
      kfr[nt] = o.v;
    }

    // ---- S = Qn * Kn^T  (16 mfma, K=32 in one step) ----
    f32x4 sv[4][4];
    const f32x4 zero = {0.f, 0.f, 0.f, 0.f};
#pragma unroll
    for (int mt = 0; mt < 4; ++mt)
#pragma unroll
      for (int nt = 0; nt < 4; ++nt)
        sv[mt][nt] = __builtin_amdgcn_mfma_f32_16x16x32_bf16(qfr[mt], kfr[nt], zero, 0, 0, 0);

    // ---- + relb (C-frag float4) + mask (bit -> 0 / -100) ----
#pragma unroll
    for (int mt = 0; mt < 4; ++mt)
#pragma unroll
      for (int nt = 0; nt < 4; ++nt) {
        float4 rb = *(const float4*)(relbC + (size_t)(((h * 4 + mt) * 4 + nt) * 4 + g) * 64 + l16 * 4);
        const unsigned char nb = mb[mt * 4 + nt];
        sv[mt][nt][0] += rb.x + ((nb & 1) ? 0.f : -100.f);
        sv[mt][nt][1] += rb.y + ((nb & 2) ? 0.f : -100.f);
        sv[mt][nt][2] += rb.z + ((nb & 4) ? 0.f : -100.f);
        sv[mt][nt][3] += rb.w + ((nb & 8) ? 0.f : -100.f);
      }

    // ---- softmax over rows (row r = mt*16 + g*4 + reg; 64 cols over nt,l16) ----
    float mx[4][4];
#pragma unroll
    for (int mt = 0; mt < 4; ++mt)
#pragma unroll
      for (int reg = 0; reg < 4; ++reg) {
        float m = fmaxf(fmaxf(sv[mt][0][reg], sv[mt][1][reg]),
                        fmaxf(sv[mt][2][reg], sv[mt][3][reg]));
#pragma unroll
        for (int st = 1; st < 16; st <<= 1) m = fmaxf(m, __shfl_xor(m, st, 64));
        mx[mt][reg] = m;
      }
#pragma unroll
    for (int mt = 0; mt < 4; ++mt)
#pragma unroll
      for (int nt = 0; nt < 4; ++nt)
#pragma unroll
        for (int reg = 0; reg < 4; ++reg)
          sv[mt][nt][reg] = __expf(sv[mt][nt][reg] - mx[mt][reg]);

    // ---- row sums -> fold 1/sum into P; pack P to bf16 (frees sv/inv) ----
    uint2 pk[4][4];
#pragma unroll
    for (int mt = 0; mt < 4; ++mt) {
      float iv[4];
#pragma unroll
      for (int reg = 0; reg < 4; ++reg) {
        float s = sv[mt][0][reg] + sv[mt][1][reg] + sv[mt][2][reg] + sv[mt][3][reg];
#pragma unroll
        for (int st = 1; st < 16; st <<= 1) s += __shfl_xor(s, st, 64);
        iv[reg] = 1.0f / s;
      }
#pragma unroll
      for (int nt = 0; nt < 4; ++nt) {
        pk[mt][nt].x = (uint32_t)f2bf(sv[mt][nt][0] * iv[0]) |
                       ((uint32_t)f2bf(sv[mt][nt][1] * iv[1]) << 16);
        pk[mt][nt].y = (uint32_t)f2bf(sv[mt][nt][2] * iv[2]) |
                       ((uint32_t)f2bf(sv[mt][nt][3] * iv[3]) << 16);
      }
    }

    // ---- PV: P (C-layout, packed) -> per-wave LDS -> A-frags; O += P * V ----
    f32x4 ov[4][2] = {};
#pragma unroll
    for (int kt = 0; kt < 2; ++kt) {
#pragma unroll
      for (int mt = 0; mt < 4; ++mt)
#pragma unroll
        for (int tjh = 0; tjh < 2; ++tjh) {
          const uint2 u = pk[mt][kt * 2 + tjh];
          Ps[wv][mt * 16 + g * 4 + 0][tjh * 16 + l16] = (ushort)(u.x);
          Ps[wv][mt * 16 + g * 4 + 1][tjh * 16 + l16] = (ushort)(u.x >> 16);
          Ps[wv][mt * 16 + g * 4 + 2][tjh * 16 + l16] = (ushort)(u.y);
          Ps[wv][mt * 16 + g * 4 + 3][tjh * 16 + l16] = (ushort)(u.y >> 16);
        }
      short8 pf[4], vf[2];
#pragma unroll
      for (int mt = 0; mt < 4; ++mt) pf[mt] = *(const short8*)&Ps[wv][mt * 16 + l16][g * 8];
#pragma unroll
      for (int n2 = 0; n2 < 2; ++n2) vf[n2] = *(const short8*)&Vt[wv][n2 * 16 + l16][kt * 32 + g * 8];
#pragma unroll
      for (int mt = 0; mt < 4; ++mt)
#pragma unroll
        for (int n2 = 0; n2 < 2; ++n2)
          ov[mt][n2] = __builtin_amdgcn_mfma_f32_16x16x32_bf16(pf[mt], vf[n2], ov[mt][n2], 0, 0, 0);
    }

    // ---- epilogue: store bf16 (rows already normalized via P) ----
#pragma unroll
    for (int mt = 0; mt < 4; ++mt)
#pragma unroll
      for (int n2 = 0; n2 < 2; ++n2)
#pragma unroll
        for (int reg = 0; reg < 4; ++reg) {
          int r = mt * 16 + g * 4 + reg;
          aob[((size_t)b * 64 + r) * 256 + h * 32 + n2 * 16 + l16] = f2bf(ov[mt][n2][reg]);
        }
  }
}

// ---------------- launch ----------------

extern "C" void kernel_launch(void* const* d_in, const int* in_sizes, int n_in,
                              void* d_out, int out_size, void* d_ws, size_t ws_size,
                              hipStream_t stream) {
  const float* x      = (const float*)d_in[0];
  const float* mask   = (const float*)d_in[1];
  const float* qkv_w  = (const float*)d_in[2];
  const float* q_bias = (const float*)d_in[3];
  const float* v_bias = (const float*)d_in[4];
  const float* lscale = (const float*)d_in[5];
  const float* ctbl   = (const float*)d_in[6];
  const float* m1w    = (const float*)d_in[7];
  const float* m1b    = (const float*)d_in[8];
  const float* m2w    = (const float*)d_in[9];
  const float* projw  = (const float*)d_in[10];
  const float* projb  = (const float*)d_in[11];
  const int*   rpi    = (const int*)d_in[12];

  char* w = (char*)d_ws;
  float*  bias_table = (float*)(w + 0);               //    7200 B
  float*  relbC      = (float*)(w + 8192);            //  131072 B
  unsigned char* maskN = (unsigned char*)(w + 139264); //  262144 B
  ushort* qkvWT      = (ushort*)(w + 4333568);        //  393216 B  [768][256] bf16
  ushort* projWT     = (ushort*)(w + 4726784);        //  131072 B  [256][256] bf16
  ushort* xb         = (ushort*)(w + 4857856);        // 67108864 B [131072][256] bf16
  ushort* qkvb       = (ushort*)(w + 71966720ull);    // 201326592 B [131072][768] bf16
  ushort* aob        = (ushort*)(w + 273293312ull);   // 67108864 B [131072][256] bf16
  (void)ws_size; (void)n_in; (void)in_sizes; (void)out_size;

  k_cast_bf16<<<4096, 256, 0, stream>>>(x, xb, MROWS * CDIM / 4);
  k_transpose_bf16<<<768, 256, 0, stream>>>(qkv_w, qkvWT, 256, 768);
  k_transpose_bf16<<<256, 256, 0, stream>>>(projw, projWT, 256, 256);
  k_cpb<<<225, 256, 0, stream>>>(ctbl, m1w, m1b, m2w, bias_table);
  k_relbC<<<128, 256, 0, stream>>>(bias_table, rpi, relbC);
  k_maskBits<<<1024, 256, 0, stream>>>(mask, maskN);

  gemm_bt<0><<<dim3(6, 1024), 256, 0, stream>>>(xb, qkvWT, qkvb, q_bias, v_bias, 256, 768);
  k_attn_mfma<<<BWIN, 256, 0, stream>>>(qkvb, maskN, lscale, relbC, aob);
  gemm_bt<1><<<dim3(2, 1024), 256, 0, stream>>>(aob, projWT, d_out, projb, nullptr, 256, 256);
}

// Round 4
// 526.682 us; speedup vs baseline: 1.2198x; 1.0058x over previous
//
#include <hip/hip_runtime.h>
#include <hip/hip_bf16.h>
#include <stdint.h>

// Problem constants
#define NTOK   64      // tokens per window
#define CDIM   256     // embed dim
#define NHEAD  8
#define DHEAD  32
#define NWIN   256     // windows per image (mask count)
#define BWIN   2048    // total windows
#define MROWS  131072  // BWIN*NTOK

typedef __attribute__((ext_vector_type(8))) short short8;
typedef __attribute__((ext_vector_type(4))) float f32x4;

__device__ __forceinline__ ushort f2bf(float f) {
  uint32_t u = __float_as_uint(f);
  u += 0x7fffu + ((u >> 16) & 1u);   // RNE
  return (ushort)(u >> 16);
}
__device__ __forceinline__ void unpack8(uint4 u, float* f) {
  f[0] = __uint_as_float(u.x << 16);
  f[1] = __uint_as_float(u.x & 0xffff0000u);
  f[2] = __uint_as_float(u.y << 16);
  f[3] = __uint_as_float(u.y & 0xffff0000u);
  f[4] = __uint_as_float(u.z << 16);
  f[5] = __uint_as_float(u.z & 0xffff0000u);
  f[6] = __uint_as_float(u.w << 16);
  f[7] = __uint_as_float(u.w & 0xffff0000u);
}

// ---------------- tiny prep kernels ----------------

__global__ void k_cast_bf16(const float* __restrict__ src, ushort* __restrict__ dst, int n4) {
  int i = blockIdx.x * blockDim.x + threadIdx.x;
  int stride = gridDim.x * blockDim.x;
  for (; i < n4; i += stride) {
    float4 v = ((const float4*)src)[i];
    ushort4 o;
    o.x = f2bf(v.x); o.y = f2bf(v.y); o.z = f2bf(v.z); o.w = f2bf(v.w);
    ((ushort4*)dst)[i] = o;
  }
}

// src[K][N] fp32 -> dst[N][K] bf16
__global__ void k_transpose_bf16(const float* __restrict__ src, ushort* __restrict__ dst, int K, int N) {
  int idx = blockIdx.x * 256 + threadIdx.x;
  if (idx < N * K) {
    int n = idx / K, k = idx - n * K;
    dst[idx] = f2bf(src[(size_t)k * N + n]);
  }
}

// CPB MLP: bias_table[225][8]
__global__ void k_cpb(const float* __restrict__ ct, const float* __restrict__ w1,
                      const float* __restrict__ b1, const float* __restrict__ w2,
                      float* __restrict__ out) {
  int p = blockIdx.x, t = threadIdx.x;
  float c0 = ct[p * 2], c1 = ct[p * 2 + 1];
  float acc[8];
#pragma unroll
  for (int h = 0; h < 8; ++h) acc[h] = 0.f;
  for (int j = t; j < 512; j += 256) {
    float hj = fmaxf(0.f, fmaf(c0, w1[j], fmaf(c1, w1[512 + j], b1[j])));
#pragma unroll
    for (int h = 0; h < 8; ++h) acc[h] = fmaf(hj, w2[j * 8 + h], acc[h]);
  }
#pragma unroll
  for (int off = 1; off < 64; off <<= 1)
#pragma unroll
    for (int h = 0; h < 8; ++h) acc[h] += __shfl_xor(acc[h], off, 64);
  __shared__ float red[4][8];
  if ((t & 63) == 0)
#pragma unroll
    for (int h = 0; h < 8; ++h) red[t >> 6][h] = acc[h];
  __syncthreads();
  if (t < 8) out[p * 8 + t] = red[0][t] + red[1][t] + red[2][t] + red[3][t];
}

// relbC for the SWAPPED (S^T) fragment order:
// idx = ((((h*4+nt)*4+mt)*4+g)*16+l16)*4+reg
// value = 16*sigmoid(bias_table[rpi[q*64+k]][h]), q = mt*16+l16, k = nt*16+g*4+reg
__global__ void k_relbC(const float* __restrict__ bt, const int* __restrict__ rpi,
                        float* __restrict__ out) {
  int idx = blockIdx.x * 256 + threadIdx.x;  // 32768 total
  int reg = idx & 3, l16 = (idx >> 2) & 15, g = (idx >> 6) & 3;
  int mt = (idx >> 8) & 3, nt = (idx >> 10) & 3, h = idx >> 12;
  int q = mt * 16 + l16, k = nt * 16 + g * 4 + reg;
  float v = bt[rpi[q * 64 + k] * 8 + h];
  out[idx] = 16.0f / (1.0f + __expf(-v));
}

// mask bits for the swapped order, packed for one-uint4-per-lane loads:
// out[wi*1024 + (g*16+l16)*16 + (nt*4+mt)] : bit reg = (mask[wi][q][k] == 0)
// with q = mt*16+l16, k = nt*16+g*4+reg.  (mask values are exactly 0 or -100)
__global__ void k_maskBits(const float* __restrict__ mask, unsigned char* __restrict__ out) {
  int idx = blockIdx.x * 256 + threadIdx.x;  // 262144 total
  int b = idx & 15;            // nt*4+mt
  int q6 = (idx >> 4) & 63;    // g*16+l16
  int wi = idx >> 10;
  int nt = b >> 2, mt = b & 3, g = q6 >> 4, l16 = q6 & 15;
  unsigned char v = 0;
#pragma unroll
  for (int reg = 0; reg < 4; ++reg) {
    int q = mt * 16 + l16, k = nt * 16 + g * 4 + reg;
    if (mask[(size_t)wi * 4096 + q * 64 + k] == 0.0f) v |= (unsigned char)(1 << reg);
  }
  out[idx] = v;
}

// ---------------- MFMA GEMM: C[M][N] = A[M][K] * BT[N][K]^T ----------------
// Reg-staged with XOR-swizzled LDS stores (round-0 form: measured ~25us faster
// end-to-end than the gload_lds variant at this tiny K=256 / nkt=4 shape).
template <int MODE>
__global__ __launch_bounds__(256, 2) void gemm_bt(const ushort* __restrict__ A,
                                                  const ushort* __restrict__ BT,
                                                  void* __restrict__ Cout,
                                                  const float* __restrict__ bias0,
                                                  const float* __restrict__ bias1,
                                                  int K, int N) {
  __shared__ ushort As[128 * 64];
  __shared__ ushort Bs[128 * 64];
  const int t = threadIdx.x;
  const int bn = blockIdx.x, bm = blockIdx.y;
  const int wv = t >> 6, lane = t & 63, quad = lane >> 4, l16 = lane & 15;
  const int mbase = (wv & 1) * 64, nbase = (wv >> 1) * 64;

  f32x4 acc[4][4] = {};

  const int nkt = K >> 6;
  for (int kt = 0; kt < nkt; ++kt) {
    __syncthreads();
#pragma unroll
    for (int i = 0; i < 4; ++i) {
      int idx = i * 256 + t;
      int m = idx >> 3, c = idx & 7;
      int sw = (m * 8 + (c ^ (m & 7))) * 8;
      *(uint4*)(As + sw) = *(const uint4*)(A + (size_t)(bm * 128 + m) * K + kt * 64 + c * 8);
      *(uint4*)(Bs + sw) = *(const uint4*)(BT + (size_t)(bn * 128 + m) * K + kt * 64 + c * 8);
    }
    __syncthreads();
#pragma unroll
    for (int k2 = 0; k2 < 2; ++k2) {
      const int cidx = (k2 * 4 + quad) ^ (l16 & 7);
      short8 a[4], b[4];
#pragma unroll
      for (int mt = 0; mt < 4; ++mt)
        a[mt] = *(const short8*)(As + ((mbase + mt * 16 + l16) * 8 + cidx) * 8);
#pragma unroll
      for (int nt = 0; nt < 4; ++nt)
        b[nt] = *(const short8*)(Bs + ((nbase + nt * 16 + l16) * 8 + cidx) * 8);
#pragma unroll
      for (int mt = 0; mt < 4; ++mt)
#pragma unroll
        for (int nt = 0; nt < 4; ++nt)
          acc[mt][nt] = __builtin_amdgcn_mfma_f32_16x16x32_bf16(a[mt], b[nt], acc[mt][nt], 0, 0, 0);
    }
  }

#pragma unroll
  for (int mt = 0; mt < 4; ++mt)
#pragma unroll
    for (int nt = 0; nt < 4; ++nt) {
      int j = bn * 128 + nbase + nt * 16 + l16;
      int gm = bm * 128 + mbase + mt * 16 + quad * 4;
      float bs;
      if (MODE == 0) bs = (j < 256) ? bias0[j] : ((j < 512) ? 0.0f : bias1[j - 512]);
      else bs = bias0[j];
#pragma unroll
      for (int i2 = 0; i2 < 4; ++i2) {
        float v = acc[mt][nt][i2] + bs;
        size_t off = (size_t)(gm + i2) * N + j;
        if (MODE == 0) ((ushort*)Cout)[off] = f2bf(v);
        else ((float*)Cout)[off] = v;
      }
    }
}

// ---------------- MFMA attention (swapped-operand S^T) ----------------
// 1 block / window, 4 fully-independent waves (wave wv owns head pass*4+wv);
// no __syncthreads (all LDS per-wave private, DS pipe in-order within a wave).
// S^T = mfma(K,Q): lane (g,l16) holds S[q=mt*16+l16][k=nt*16+g*4+reg] -> row
// softmax is 15 in-lane ops + TWO shfl_xor (16,32) instead of 4-deep chains
// (128 -> 16 ds_swizzle per pass). P's k-values are lane-contiguous -> the
// P->LDS round trip is 16 ds_write_b64 into a full P[64][72] buffer written
// once per pass (vs 64 scalar writes), read by both PV K-steps as b128.
// (256,2): total unified-reg cap 256, no spill (round-2 lesson).
__global__ __launch_bounds__(256, 2) void k_attn_mfma(const ushort* __restrict__ qkv,
                                                      const unsigned char* __restrict__ maskN,
                                                      const float* __restrict__ ls,
                                                      const float* __restrict__ relbC,
                                                      ushort* __restrict__ aob) {
  __shared__ ushort Vt[4][32][72];
  __shared__ ushort Ps[4][64][72];
  const int b = blockIdx.x, t = threadIdx.x;
  const int wi = b & (NWIN - 1);
  const int wv = t >> 6, lane = t & 63;
  const int g = lane >> 4, l16 = lane & 15;
  const size_t rowb = (size_t)b * 64;

  // ---- mask bits for this (window, lane): 16 nibbles, one per (nt,mt) ----
  const uint4 mbits = *(const uint4*)(maskN + (size_t)wi * 1024 + (g * 16 + l16) * 16);
  const unsigned char* mb = (const unsigned char*)&mbits;

  for (int pass = 0; pass < 2; ++pass) {
    const int h = pass * 4 + wv;

    // ---- V -> Vt[wv] (transposed; per-wave private) ----
    {
      const int tok = lane;
      const size_t base = (rowb + tok) * 768 + 512 + h * 32;
      union { uint4 u[4]; ushort s[32]; } raw;
      raw.u[0] = *(const uint4*)(qkv + base);
      raw.u[1] = *(const uint4*)(qkv + base + 8);
      raw.u[2] = *(const uint4*)(qkv + base + 16);
      raw.u[3] = *(const uint4*)(qkv + base + 24);
#pragma unroll
      for (int d = 0; d < 32; ++d) Vt[wv][d][tok] = raw.s[d];
    }

    // ---- Q fragments: direct global load + in-register norm (+ logit scale) ----
    const float sc = __expf(fminf(ls[h], 4.6051701859880914f));
    short8 qfr[4], kfr[4];
#pragma unroll
    for (int mt = 0; mt < 4; ++mt) {
      uint4 r = *(const uint4*)(qkv + (rowb + mt * 16 + l16) * 768 + h * 32 + g * 8);
      float f[8];
      unpack8(r, f);
      float s = 0.f;
#pragma unroll
      for (int j = 0; j < 8; ++j) s = fmaf(f[j], f[j], s);
      s += __shfl_xor(s, 16, 64);
      s += __shfl_xor(s, 32, 64);
      const float fac = sc / fmaxf(sqrtf(s), 1e-12f);
      union { short8 v; ushort us[8]; } o;
#pragma unroll
      for (int j = 0; j < 8; ++j) o.us[j] = f2bf(f[j] * fac);
      qfr[mt] = o.v;
    }
    // ---- K fragments: same, without logit scale ----
#pragma unroll
    for (int nt = 0; nt < 4; ++nt) {
      uint4 r = *(const uint4*)(qkv + (rowb + nt * 16 + l16) * 768 + 256 + h * 32 + g * 8);
      float f[8];
      unpack8(r, f);
      float s = 0.f;
#pragma unroll
      for (int j = 0; j < 8; ++j) s = fmaf(f[j], f[j], s);
      s += __shfl_xor(s, 16, 64);
      s += __shfl_xor(s, 32, 64);
      const float fac = 1.0f / fmaxf(sqrtf(s), 1e-12f);
      union { short8 v; ushort us[8]; } o;
#pragma unroll
      for (int j = 0; j < 8; ++j) o.us[j] = f2bf(f[j] * fac);
      kfr[nt] = o.v;
    }

    // ---- S^T = Kn * Qn^T  (16 mfma; sv[nt][mt], rows=k, cols=q) ----
    f32x4 sv[4][4];
    const f32x4 zero = {0.f, 0.f, 0.f, 0.f};
#pragma unroll
    for (int nt = 0; nt < 4; ++nt)
#pragma unroll
      for (int mt = 0; mt < 4; ++mt)
        sv[nt][mt] = __builtin_amdgcn_mfma_f32_16x16x32_bf16(kfr[nt], qfr[mt], zero, 0, 0, 0);

    // ---- + relb (swapped C-frag float4 over reg) + mask (bit -> 0 / -100) ----
#pragma unroll
    for (int nt = 0; nt < 4; ++nt)
#pragma unroll
      for (int mt = 0; mt < 4; ++mt) {
        float4 rb = *(const float4*)(relbC + (size_t)(((h * 4 + nt) * 4 + mt) * 4 + g) * 64 + l16 * 4);
        const unsigned char nb = mb[nt * 4 + mt];
        sv[nt][mt][0] += rb.x + ((nb & 1) ? 0.f : -100.f);
        sv[nt][mt][1] += rb.y + ((nb & 2) ? 0.f : -100.f);
        sv[nt][mt][2] += rb.z + ((nb & 4) ? 0.f : -100.f);
        sv[nt][mt][3] += rb.w + ((nb & 8) ? 0.f : -100.f);
      }

    // ---- softmax per q-row (row = mt*16+l16; 16 in-lane vals + cross-g) ----
    // then fold 1/sum into P, pack bf16, ds_write_b64 into Ps[q][k]
#pragma unroll
    for (int mt = 0; mt < 4; ++mt) {
      float m = sv[0][mt][0];
#pragma unroll
      for (int nt = 0; nt < 4; ++nt)
#pragma unroll
        for (int reg = 0; reg < 4; ++reg) m = fmaxf(m, sv[nt][mt][reg]);
      m = fmaxf(m, __shfl_xor(m, 16, 64));
      m = fmaxf(m, __shfl_xor(m, 32, 64));
      float s = 0.f;
#pragma unroll
      for (int nt = 0; nt < 4; ++nt)
#pragma unroll
        for (int reg = 0; reg < 4; ++reg) {
          float e = __expf(sv[nt][mt][reg] - m);
          sv[nt][mt][reg] = e;
          s += e;
        }
      s += __shfl_xor(s, 16, 64);
      s += __shfl_xor(s, 32, 64);
      const float iv = 1.0f / s;
#pragma unroll
      for (int nt = 0; nt < 4; ++nt) {
        uint2 u;
        u.x = (uint32_t)f2bf(sv[nt][mt][0] * iv) | ((uint32_t)f2bf(sv[nt][mt][1] * iv) << 16);
        u.y = (uint32_t)f2bf(sv[nt][mt][2] * iv) | ((uint32_t)f2bf(sv[nt][mt][3] * iv) << 16);
        *(uint2*)&Ps[wv][mt * 16 + l16][nt * 16 + g * 4] = u;
      }
    }

    // ---- PV: A-frags from Ps, B-frags from Vt; O += P * V ----
    f32x4 ov[4][2] = {};
#pragma unroll
    for (int kt = 0; kt < 2; ++kt) {
      short8 pf[4], vf[2];
#pragma unroll
      for (int mt = 0; mt < 4; ++mt) pf[mt] = *(const short8*)&Ps[wv][mt * 16 + l16][kt * 32 + g * 8];
#pragma unroll
      for (int n2 = 0; n2 < 2; ++n2) vf[n2] = *(const short8*)&Vt[wv][n2 * 16 + l16][kt * 32 + g * 8];
#pragma unroll
      for (int mt = 0; mt < 4; ++mt)
#pragma unroll
        for (int n2 = 0; n2 < 2; ++n2)
          ov[mt][n2] = __builtin_amdgcn_mfma_f32_16x16x32_bf16(pf[mt], vf[n2], ov[mt][n2], 0, 0, 0);
    }

    // ---- epilogue: store bf16 (rows already normalized via P) ----
#pragma unroll
    for (int mt = 0; mt < 4; ++mt)
#pragma unroll
      for (int n2 = 0; n2 < 2; ++n2)
#pragma unroll
        for (int reg = 0; reg < 4; ++reg) {
          int r = mt * 16 + g * 4 + reg;
          aob[((size_t)b * 64 + r) * 256 + h * 32 + n2 * 16 + l16] = f2bf(ov[mt][n2][reg]);
        }
  }
}

// ---------------- launch ----------------

extern "C" void kernel_launch(void* const* d_in, const int* in_sizes, int n_in,
                              void* d_out, int out_size, void* d_ws, size_t ws_size,
                              hipStream_t stream) {
  const float* x      = (const float*)d_in[0];
  const float* mask   = (const float*)d_in[1];
  const float* qkv_w  = (const float*)d_in[2];
  const float* q_bias = (const float*)d_in[3];
  const float* v_bias = (const float*)d_in[4];
  const float* lscale = (const float*)d_in[5];
  const float* ctbl   = (const float*)d_in[6];
  const float* m1w    = (const float*)d_in[7];
  const float* m1b    = (const float*)d_in[8];
  const float* m2w    = (const float*)d_in[9];
  const float* projw  = (const float*)d_in[10];
  const float* projb  = (const float*)d_in[11];
  const int*   rpi    = (const int*)d_in[12];

  char* w = (char*)d_ws;
  float*  bias_table = (float*)(w + 0);               //    7200 B
  float*  relbC      = (float*)(w + 8192);            //  131072 B
  unsigned char* maskN = (unsigned char*)(w + 139264); //  262144 B
  ushort* qkvWT      = (ushort*)(w + 4333568);        //  393216 B  [768][256] bf16
  ushort* projWT     = (ushort*)(w + 4726784);        //  131072 B  [256][256] bf16
  ushort* xb         = (ushort*)(w + 4857856);        // 67108864 B [131072][256] bf16
  ushort* qkvb       = (ushort*)(w + 71966720ull);    // 201326592 B [131072][768] bf16
  ushort* aob        = (ushort*)(w + 273293312ull);   // 67108864 B [131072][256] bf16
  (void)ws_size; (void)n_in; (void)in_sizes; (void)out_size;

  k_cast_bf16<<<4096, 256, 0, stream>>>(x, xb, MROWS * CDIM / 4);
  k_transpose_bf16<<<768, 256, 0, stream>>>(qkv_w, qkvWT, 256, 768);
  k_transpose_bf16<<<256, 256, 0, stream>>>(projw, projWT, 256, 256);
  k_cpb<<<225, 256, 0, stream>>>(ctbl, m1w, m1b, m2w, bias_table);
  k_relbC<<<128, 256, 0, stream>>>(bias_table, rpi, relbC);
  k_maskBits<<<1024, 256, 0, stream>>>(mask, maskN);

  gemm_bt<0><<<dim3(6, 1024), 256, 0, stream>>>(xb, qkvWT, qkvb, q_bias, v_bias, 256, 768);
  k_attn_mfma<<<BWIN, 256, 0, stream>>>(qkvb, maskN, lscale, relbC, aob);
  gemm_bt<1><<<dim3(2, 1024), 256, 0, stream>>>(aob, projWT, d_out, projb, nullptr, 256, 256);
}